// Round 5
// baseline (941.000 us; speedup 1.0000x reference)
//
#include <hip/hip_runtime.h>
#include <stdint.h>

typedef unsigned short u16;
typedef unsigned int u32;
typedef __attribute__((ext_vector_type(8))) short s8v;   // 8 bf16 = 4 VGPR (MFMA A/B frag)
typedef __attribute__((ext_vector_type(4))) float f4v;   // MFMA C/D frag
typedef __attribute__((ext_vector_type(8))) u16 u16x8;

// ---------- bf16 helpers ----------
__device__ __forceinline__ float bf2f(u16 u){
  union { u32 i; float f; } v; v.i = ((u32)u) << 16; return v.f;
}
__device__ __forceinline__ u16 f2bf(float f){
  union { float f; u32 i; } v; v.f = f;
  u32 i = v.i;
  return (u16)((i + 0x7fffu + ((i >> 16) & 1u)) >> 16); // RNE
}
__device__ __forceinline__ float sgnf(float w){
  return (w > 0.f) ? 1.f : ((w < 0.f) ? -1.f : 0.f);
}
__device__ __forceinline__ u16 sgn_bf(float w){
  return (w > 0.f) ? (u16)0x3F80 : ((w < 0.f) ? (u16)0xBF80 : (u16)0);
}

// ---------- block reduction (256 threads = 4 waves) ----------
__device__ __forceinline__ void block_reduce2(float& a, float& b){
  #pragma unroll
  for (int off = 32; off > 0; off >>= 1){
    a += __shfl_down(a, off);
    b += __shfl_down(b, off);
  }
  __shared__ float ra[4], rb[4];
  int lane = threadIdx.x & 63, w = threadIdx.x >> 6;
  __syncthreads();
  if (lane == 0){ ra[w] = a; rb[w] = b; }
  __syncthreads();
  if (threadIdx.x == 0){
    a = ra[0] + ra[1] + ra[2] + ra[3];
    b = rb[0] + rb[1] + rb[2] + rb[3];
  }
}

__global__ void k_zero(float* __restrict__ p, int n){
  int i = blockIdx.x * blockDim.x + threadIdx.x;
  if (i < n) p[i] = 0.f;
}

// ---------- sum(|w|) for the 4 weight tensors ----------
__global__ __launch_bounds__(256) void k_absum(const float* __restrict__ w1, const float* __restrict__ w2,
                                               const float* __restrict__ wfc1, const float* __restrict__ wfc2,
                                               float* __restrict__ absum){
  int b = blockIdx.x, t = threadIdx.x;
  const float* src; int n0, cnt, slot;
  if (b < 64)      { src = wfc1; slot = 2; cnt = 2097152/64; n0 = b * cnt; }
  else if (b < 96) { src = w2;   slot = 1; cnt = 73728/32;   n0 = (b-64) * cnt; }
  else if (b == 96){ src = w1;   slot = 0; cnt = 1728;       n0 = 0; }
  else             { src = wfc2; slot = 3; cnt = 2560;       n0 = 0; }
  float s = 0.f, d = 0.f;
  for (int i = t; i < cnt; i += 256) s += fabsf(src[n0 + i]);
  block_reduce2(s, d);
  if (t == 0) atomicAdd(absum + slot, s);
}

// ---------- generate all quantized weight forms ----------
// qw1t: fp32 [27 k][64 co] for conv1 VALU
// qw2b: bf16 MFMA B-frags for conv2, frag fid=(s*2+ks)*8+nt, elem idx=fid*512+lane*8+j
//       co = (lane&15)*8 + nt   (co permutation -> coalesced channel-last stores)
//       c  = ks*32 + (lane>>4)*8 + j
// qfc1b: bf16 MFMA B-frags for fc1, frag = kstep*16+nt; k_phys = kstep*32+(lane>>4)*8+j
//       p2 is channel-last: k_phys = px*128+c  ->  logical k = c*64+px
// qwfc2: fp32 sign [10][256]
__global__ __launch_bounds__(256) void k_signgen(const float* __restrict__ w1, const float* __restrict__ w2,
                                                 const float* __restrict__ wfc1, const float* __restrict__ wfc2,
                                                 float* __restrict__ qw1t, u16* __restrict__ qw2b,
                                                 u16* __restrict__ qfc1b, float* __restrict__ qwfc2){
  int i = blockIdx.x * 256 + threadIdx.x;
  if (i < 2097152){
    int j = i & 7, lane = (i >> 3) & 63, fid = i >> 9;
    int kstep = fid >> 4, nt = fid & 15;
    int co = nt*16 + (lane & 15);
    int k_phys = kstep*32 + (lane >> 4)*8 + j;
    int px = k_phys >> 7, c = k_phys & 127;
    qfc1b[i] = sgn_bf(wfc1[(size_t)co*8192 + c*64 + px]);
  } else if (i < 2097152 + 73728){
    int i2 = i - 2097152;
    int j = i2 & 7, lane = (i2 >> 3) & 63, fid = i2 >> 9;  // 0..143
    int s = fid >> 4, ks = (fid >> 3) & 1, nt = fid & 7;
    int co = (lane & 15)*8 + nt;
    int c = ks*32 + (lane >> 4)*8 + j;
    qw2b[i2] = sgn_bf(w2[((size_t)co*64 + c)*9 + s]);
  } else if (i < 2097152 + 73728 + 1728){
    int i3 = i - (2097152 + 73728);
    int co = i3 / 27, k = i3 % 27;
    qw1t[k*64 + co] = sgnf(w1[i3]);
  } else if (i < 2097152 + 73728 + 1728 + 2560){
    int i4 = i - (2097152 + 73728 + 1728);
    qwfc2[i4] = sgnf(wfc2[i4]);
  }
}

// ---------- conv1 pass A: x[1024,3,32,32] fp32 -> BN1 sum/sumsq only (no h1 store) ----------
__global__ __launch_bounds__(256, 4) void k_conv1s(const float* __restrict__ x, const float* __restrict__ qw1t,
                                                   const float* __restrict__ absum,
                                                   float* __restrict__ gs, float* __restrict__ gq){
  __shared__ float xs[3*34*36]; // [ci][y 0..33][x 0..35], data y=1..32, x=2..33
  __shared__ float ls1[64], ls2[64];
  int n = blockIdx.x, t = threadIdx.x;
  if (t < 64){ ls1[t] = 0.f; ls2[t] = 0.f; }
  for (int i = t; i < 3672; i += 256) xs[i] = 0.f;
  __syncthreads();
  const float4* xg = (const float4*)(x + (size_t)n * 3072);
  for (int i = t; i < 768; i += 256){
    float4 v = xg[i];
    int ci = i >> 8, rem = i & 255, y = rem >> 3, xq = (rem & 7) * 4;
    int base = ci*1224 + (y+1)*36 + 2 + xq;
    xs[base+0] = v.x; xs[base+1] = v.y; xs[base+2] = v.z; xs[base+3] = v.w;
  }
  __syncthreads();
  int lane = t & 63;
  int yy0[4], xx0[4];
  #pragma unroll
  for (int s = 0; s < 4; ++s){ int sp = t + 256*s; yy0[s] = sp >> 5; xx0[s] = sp & 31; }
  for (int cc = 0; cc < 8; ++cc){
    float acc[4][8];
    #pragma unroll
    for (int s = 0; s < 4; ++s)
      #pragma unroll
      for (int r = 0; r < 8; ++r) acc[s][r] = 0.f;
    for (int ci = 0; ci < 3; ++ci){
      #pragma unroll
      for (int dy = 0; dy < 3; ++dy){
        #pragma unroll
        for (int dx = 0; dx < 3; ++dx){
          int k = ci*9 + dy*3 + dx;
          float wv[8];
          #pragma unroll
          for (int r = 0; r < 8; ++r) wv[r] = qw1t[k*64 + cc*8 + r]; // uniform -> s_load
          #pragma unroll
          for (int s = 0; s < 4; ++s){
            float a = xs[ci*1224 + (yy0[s]+dy)*36 + (xx0[s]+dx+1)];
            #pragma unroll
            for (int r = 0; r < 8; ++r) acc[s][r] += a * wv[r];
          }
        }
      }
    }
    // fused stats on raw conv values (alpha applied once at the end)
    float s1v[8], s2v[8];
    #pragma unroll
    for (int r = 0; r < 8; ++r){
      s1v[r] = acc[0][r] + acc[1][r] + acc[2][r] + acc[3][r];
      s2v[r] = acc[0][r]*acc[0][r] + acc[1][r]*acc[1][r] + acc[2][r]*acc[2][r] + acc[3][r]*acc[3][r];
    }
    #pragma unroll
    for (int r = 0; r < 8; ++r){
      #pragma unroll
      for (int off = 32; off > 0; off >>= 1){
        s1v[r] += __shfl_xor(s1v[r], off);
        s2v[r] += __shfl_xor(s2v[r], off);
      }
    }
    if (lane == 0){
      #pragma unroll
      for (int r = 0; r < 8; ++r){
        atomicAdd(&ls1[cc*8 + r], s1v[r]);
        atomicAdd(&ls2[cc*8 + r], s2v[r]);
      }
    }
  }
  __syncthreads();
  float alpha = absum[0] * (1.f/1728.f);
  if (t < 64){
    atomicAdd(gs + t, ls1[t] * alpha);
    atomicAdd(gq + t, ls2[t] * alpha * alpha);
  }
}

// ---------- finalize BN affine params ----------
__global__ void k_fin(const float* __restrict__ sum, const float* __restrict__ sumsq,
                      const float* __restrict__ g, const float* __restrict__ b,
                      float* __restrict__ scale, float* __restrict__ bias, int C, float invc){
  int c = blockIdx.x * blockDim.x + threadIdx.x;
  if (c >= C) return;
  float m = sum[c] * invc;
  float var = sumsq[c] * invc - m*m;
  float sc = g[c] * rsqrtf(var + 1e-5f);
  scale[c] = sc;
  bias[c] = b[c] - m * sc;
}

// ---------- conv1 pass B: recompute conv, BN+ReLU+2x2pool in-register -> p1t[1024][256px][64c] ----------
// alpha>0 and scale>0 (g=1), so max-then-affine == affine-then-max (exact)
__global__ __launch_bounds__(256, 4) void k_conv1p(const float* __restrict__ x, const float* __restrict__ qw1t,
                                                   const float* __restrict__ absum,
                                                   const float* __restrict__ sc, const float* __restrict__ bi,
                                                   u16* __restrict__ p1t){
  __shared__ float xs[3*34*36];
  __shared__ float lsc[64], lbi[64];
  int n = blockIdx.x, t = threadIdx.x;
  if (t < 64) lsc[t] = sc[t];
  else if (t < 128) lbi[t - 64] = bi[t - 64];
  for (int i = t; i < 3672; i += 256) xs[i] = 0.f;
  __syncthreads();
  const float4* xg = (const float4*)(x + (size_t)n * 3072);
  for (int i = t; i < 768; i += 256){
    float4 v = xg[i];
    int ci = i >> 8, rem = i & 255, y = rem >> 3, xq = (rem & 7) * 4;
    int base = ci*1224 + (y+1)*36 + 2 + xq;
    xs[base+0] = v.x; xs[base+1] = v.y; xs[base+2] = v.z; xs[base+3] = v.w;
  }
  __syncthreads();
  float alpha = absum[0] * (1.f/1728.f);
  int oy = t >> 4, ox = t & 15;   // output pixel; quad = input (2oy+sy, 2ox+sx)
  u16x8 pk[8];
  for (int cc = 0; cc < 8; ++cc){
    float acc[4][8];
    #pragma unroll
    for (int s = 0; s < 4; ++s)
      #pragma unroll
      for (int r = 0; r < 8; ++r) acc[s][r] = 0.f;
    for (int ci = 0; ci < 3; ++ci){
      #pragma unroll
      for (int dy = 0; dy < 3; ++dy){
        #pragma unroll
        for (int dx = 0; dx < 3; ++dx){
          int k = ci*9 + dy*3 + dx;
          float wv[8];
          #pragma unroll
          for (int r = 0; r < 8; ++r) wv[r] = qw1t[k*64 + cc*8 + r];
          #pragma unroll
          for (int s = 0; s < 4; ++s){
            float a = xs[ci*1224 + (2*oy + (s>>1) + dy)*36 + (2*ox + (s&1) + dx + 1)];
            #pragma unroll
            for (int r = 0; r < 8; ++r) acc[s][r] += a * wv[r];
          }
        }
      }
    }
    #pragma unroll
    for (int r = 0; r < 8; ++r){
      float m = fmaxf(fmaxf(acc[0][r], acc[1][r]), fmaxf(acc[2][r], acc[3][r])) * alpha;
      int c = cc*8 + r;
      pk[cc][r] = f2bf(fmaxf(m * lsc[c] + lbi[c], 0.f));
    }
  }
  u16* dst = p1t + ((size_t)n*256 + t)*64;
  #pragma unroll
  for (int cc = 0; cc < 8; ++cc) *(u16x8*)(dst + cc*8) = pk[cc];
}

// ---------- conv2 via MFMA, barrier-free K-loop ----------
// p1t[1024][256px][64c] -> h2t[1024][256px][128co] bf16 (co permutation baked into qw2b).
// Fused BN2 stats. Per block: one image. Wave w: rows y = w*4..w*4+3, all 128 co.
__global__ __launch_bounds__(256, 2) void k_conv2m(const u16* __restrict__ p1t, const u16* __restrict__ qw2b,
                                                   const float* __restrict__ absum, u16* __restrict__ h2t,
                                                   float* __restrict__ gs, float* __restrict__ gq){
  __shared__ __align__(16) u16 img[16384];   // 32 KB, XOR-swizzled 16B units
  __shared__ float ls1[128], ls2[128];
  int n = blockIdx.x, t = threadIdx.x;
  if (t < 128){ ls1[t] = 0.f; ls2[t] = 0.f; }
  const u16* src = p1t + (size_t)n * 16384;
  #pragma unroll
  for (int i = 0; i < 8; ++i){
    int id = i*256 + t;            // = px*8 + unit
    int px = id >> 3, unit = id & 7;
    int su = unit ^ (px & 7);
    *(u16x8*)(img + px*64 + su*8) = *(const u16x8*)(src + id*8);
  }
  __syncthreads();
  int w = t >> 6, lane = t & 63, l15 = lane & 15, q = lane >> 4;
  const s8v* bp = (const s8v*)qw2b;
  f4v acc[4][8];
  #pragma unroll
  for (int a = 0; a < 4; ++a)
    #pragma unroll
    for (int b = 0; b < 8; ++b) acc[a][b] = (f4v)(0.0f);
  for (int dy = 0; dy < 3; ++dy){
    for (int dx = 0; dx < 3; ++dx){
      int s = dy*3 + dx;
      int xv = l15 + dx - 1;
      bool vx = (xv >= 0) && (xv < 16);
      int xc = min(max(xv, 0), 15);
      #pragma unroll
      for (int ks = 0; ks < 2; ++ks){
        s8v bf[8];
        #pragma unroll
        for (int nt = 0; nt < 8; ++nt) bf[nt] = bp[((s*2 + ks)*8 + nt)*64 + lane];
        #pragma unroll
        for (int mt = 0; mt < 4; ++mt){
          int yv = w*4 + mt + dy - 1;
          if (yv < 0 || yv > 15) continue;
          int px = yv*16 + xc;
          int su = (ks*4 + q) ^ (px & 7);
          s8v av = *(const s8v*)(img + px*64 + su*8);
          if (!vx) av = (s8v)(short)0;
          #pragma unroll
          for (int nt = 0; nt < 8; ++nt)
            acc[mt][nt] = __builtin_amdgcn_mfma_f32_16x16x32_bf16(av, bf[nt], acc[mt][nt], 0, 0, 0);
        }
      }
    }
  }
  float alpha = absum[1] * (1.f/73728.f);
  float s1v[8], s2v[8];
  #pragma unroll
  for (int nt = 0; nt < 8; ++nt){ s1v[nt] = 0.f; s2v[nt] = 0.f; }
  #pragma unroll
  for (int mt = 0; mt < 4; ++mt){
    int y = w*4 + mt;
    #pragma unroll
    for (int r = 0; r < 4; ++r){
      int px = y*16 + q*4 + r;
      u16x8 pk;
      #pragma unroll
      for (int nt = 0; nt < 8; ++nt){
        float v = acc[mt][nt][r] * alpha;
        s1v[nt] += v; s2v[nt] += v*v;
        pk[nt] = f2bf(v);
      }
      *(u16x8*)(h2t + ((size_t)n*256 + px)*128 + l15*8) = pk;
    }
  }
  #pragma unroll
  for (int nt = 0; nt < 8; ++nt){
    s1v[nt] += __shfl_xor(s1v[nt], 16); s1v[nt] += __shfl_xor(s1v[nt], 32);
    s2v[nt] += __shfl_xor(s2v[nt], 16); s2v[nt] += __shfl_xor(s2v[nt], 32);
  }
  if (q == 0){
    #pragma unroll
    for (int nt = 0; nt < 8; ++nt){
      atomicAdd(&ls1[l15*8 + nt], s1v[nt]);
      atomicAdd(&ls2[l15*8 + nt], s2v[nt]);
    }
  }
  __syncthreads();
  if (t < 128){ atomicAdd(gs + t, ls1[t]); atomicAdd(gq + t, ls2[t]); }
}

// ---------- BN2+ReLU+pool channel-last: h2t[1024][16x16][128] -> p2[1024][8x8][128] ----------
__global__ __launch_bounds__(256) void k_pool2t(const u16* __restrict__ h2t, u16* __restrict__ p2,
                                                const float* __restrict__ sc, const float* __restrict__ bi){
  __shared__ float lsc[128], lbi[128];
  int n = blockIdx.x, t = threadIdx.x;
  if (t < 128) lsc[t] = sc[t];
  else lbi[t - 128] = bi[t - 128];
  __syncthreads();
  int opx = t >> 2, cq = t & 3;
  int oy = opx >> 3, ox = opx & 7;
  const u16* base = h2t + (size_t)n*32768 + ((oy*2)*16 + ox*2)*128 + cq*32;
  u16* dst = p2 + (size_t)n*8192 + opx*128 + cq*32;
  #pragma unroll
  for (int v = 0; v < 4; ++v){
    u16x8 a0 = *(const u16x8*)(base + v*8);
    u16x8 a1 = *(const u16x8*)(base + 128 + v*8);
    u16x8 a2 = *(const u16x8*)(base + 2048 + v*8);
    u16x8 a3 = *(const u16x8*)(base + 2176 + v*8);
    u16x8 o;
    #pragma unroll
    for (int j = 0; j < 8; ++j){
      int c = cq*32 + v*8 + j;
      float m = fmaxf(fmaxf(bf2f(a0[j]), bf2f(a1[j])), fmaxf(bf2f(a2[j]), bf2f(a3[j])));
      o[j] = f2bf(fmaxf(m * lsc[c] + lbi[c], 0.f));
    }
    *(u16x8*)(dst + v*8) = o;
  }
}

// ---------- fc1 via MFMA, k-split 16: p2[1024][8192] x signs -> h3p[16][1024][256] ----------
__global__ __launch_bounds__(256) void k_fc1m(const u16* __restrict__ p2, const u16* __restrict__ qfc1b,
                                              const float* __restrict__ absum, float* __restrict__ h3p){
  int t = threadIdx.x;
  int bm = blockIdx.x, bn = blockIdx.y, kb = blockIdx.z;
  int w = t >> 6, lane = t & 63, l15 = lane & 15, q = lane >> 4;
  int rowbase = bm*128 + (w >> 1)*64;
  int ntb = bn*8 + (w & 1)*4;
  const s8v* bp = (const s8v*)qfc1b;
  f4v acc[4][4];
  #pragma unroll
  for (int a = 0; a < 4; ++a)
    #pragma unroll
    for (int b = 0; b < 4; ++b) acc[a][b] = (f4v)(0.0f);
  #pragma unroll 2
  for (int ks = 0; ks < 16; ++ks){
    int kst = kb*16 + ks;
    s8v bf[4], af[4];
    #pragma unroll
    for (int nt = 0; nt < 4; ++nt) bf[nt] = bp[(kst*16 + ntb + nt)*64 + lane];
    #pragma unroll
    for (int mt = 0; mt < 4; ++mt)
      af[mt] = *(const s8v*)(p2 + (size_t)(rowbase + mt*16 + l15)*8192 + kst*32 + q*8);
    #pragma unroll
    for (int mt = 0; mt < 4; ++mt)
      #pragma unroll
      for (int nt = 0; nt < 4; ++nt)
        acc[mt][nt] = __builtin_amdgcn_mfma_f32_16x16x32_bf16(af[mt], bf[nt], acc[mt][nt], 0, 0, 0);
  }
  float alpha = absum[2] * (1.f/2097152.f);
  float* dst = h3p + (size_t)kb * 262144;
  #pragma unroll
  for (int mt = 0; mt < 4; ++mt)
    #pragma unroll
    for (int nt = 0; nt < 4; ++nt){
      int col = (ntb + nt)*16 + l15;
      #pragma unroll
      for (int r = 0; r < 4; ++r)
        dst[(size_t)(rowbase + mt*16 + q*4 + r)*256 + col] = acc[mt][nt][r] * alpha;
    }
}

// ---------- reduce k-split slabs + BN3 stats + materialize h3 ----------
__global__ __launch_bounds__(256) void k_fin3f(const float* __restrict__ h3p, float* __restrict__ h3,
                                               float* __restrict__ s3, float* __restrict__ q3){
  int jb = blockIdx.x, ns = blockIdx.y, t = threadIdx.x;
  int jj = t & 31, nn = t >> 5;
  int j = jb*32 + jj;
  float s1 = 0.f, s2 = 0.f;
  for (int i = nn; i < 128; i += 8){
    int n = i*8 + ns;
    float v = 0.f;
    #pragma unroll 8
    for (int kb = 0; kb < 16; ++kb) v += h3p[(size_t)kb*262144 + n*256 + j];
    h3[n*256 + j] = v;
    s1 += v; s2 += v*v;
  }
  __shared__ float l1[256], l2[256];
  l1[t] = s1; l2[t] = s2;
  __syncthreads();
  if (t < 32){
    float a = 0.f, b = 0.f;
    #pragma unroll
    for (int k = 0; k < 8; ++k){ a += l1[t+32*k]; b += l2[t+32*k]; }
    atomicAdd(s3 + jb*32 + t, a); atomicAdd(q3 + jb*32 + t, b);
  }
}

// ---------- fc2: relu(bn3(h3)) @ sign(wfc2)^T -> out[1024,10] fp32 ----------
__global__ __launch_bounds__(64) void k_fc2(const float* __restrict__ h3, const float* __restrict__ qwfc2,
                                            const float* __restrict__ absum, const float* __restrict__ scale,
                                            const float* __restrict__ bias, float* __restrict__ out){
  int n = blockIdx.x, lane = threadIdx.x;
  float a[4];
  #pragma unroll
  for (int i = 0; i < 4; ++i){
    int j = lane + 64*i;
    float v = h3[(size_t)n*256 + j] * scale[j] + bias[j];
    a[i] = fmaxf(v, 0.f);
  }
  float alpha = absum[3] * (1.f/2560.f);
  #pragma unroll
  for (int k = 0; k < 10; ++k){
    float p = 0.f;
    #pragma unroll
    for (int i = 0; i < 4; ++i) p += a[i] * qwfc2[k*256 + lane + 64*i];
    #pragma unroll
    for (int off = 32; off > 0; off >>= 1) p += __shfl_down(p, off);
    if (lane == 0) out[n*10 + k] = p * alpha;
  }
}

extern "C" void kernel_launch(void* const* d_in, const int* in_sizes, int n_in,
                              void* d_out, int out_size, void* d_ws, size_t ws_size,
                              hipStream_t stream){
  (void)in_sizes; (void)n_in; (void)out_size; (void)ws_size;
  const float* x    = (const float*)d_in[0];
  const float* w1   = (const float*)d_in[1];
  const float* g1   = (const float*)d_in[2];
  const float* b1   = (const float*)d_in[3];
  const float* w2   = (const float*)d_in[4];
  const float* g2   = (const float*)d_in[5];
  const float* b2   = (const float*)d_in[6];
  const float* wfc1 = (const float*)d_in[7];
  const float* g3   = (const float*)d_in[8];
  const float* b3   = (const float*)d_in[9];
  const float* wfc2 = (const float*)d_in[10];
  float* out = (float*)d_out;

  float* wsf = (float*)d_ws;
  char*  wsb = (char*)d_ws;
  float* absum = wsf;
  float* s1 = wsf + 16;   float* q1 = wsf + 80;
  float* s2 = wsf + 144;  float* q2 = wsf + 272;
  float* s3 = wsf + 1024; float* q3 = wsf + 1280;
  float* sc1 = wsf + 1536; float* bi1 = wsf + 1600;
  float* sc2 = wsf + 1664; float* bi2 = wsf + 1792;
  float* sc3 = wsf + 2048; float* bi3 = wsf + 2304;
  float* qw1t  = wsf + 4096;                         // 1728 fp32
  u16*   qw2b  = (u16*)(wsb + (64u << 10));          // 144 KB bf16 B-frags
  float* qwfc2 = (float*)(wsb + (256u << 10));       // 10 KB fp32
  float* h3    = (float*)(wsb + (1ull << 20));       // 1 MB fp32 [1024][256]
  u16*   qfc1b = (u16*)(wsb + (2ull << 20));         // 4 MB bf16 B-frags
  u16*   p1t   = (u16*)(wsb + (8ull << 20) + 4096);  // 32 MB bf16 [1024][256][64]
  u16*   h2t   = (u16*)(wsb + (48ull << 20));        // 64 MB bf16 [1024][256][128]
  u16*   p2    = (u16*)(wsb + (112ull << 20));       // 16 MB bf16 [1024][8192] (channel-last k)
  float* h3p   = (float*)(wsb + (128ull << 20));     // 16 MB fp32 [16][1024][256]

  k_zero<<<10, 256, 0, stream>>>(wsf, 2560);
  k_absum<<<98, 256, 0, stream>>>(w1, w2, wfc1, wfc2, absum);
  k_signgen<<<8498, 256, 0, stream>>>(w1, w2, wfc1, wfc2, qw1t, qw2b, qfc1b, qwfc2);
  k_conv1s<<<1024, 256, 0, stream>>>(x, qw1t, absum, s1, q1);
  k_fin<<<1, 64, 0, stream>>>(s1, q1, g1, b1, sc1, bi1, 64, 1.f/1048576.f);
  k_conv1p<<<1024, 256, 0, stream>>>(x, qw1t, absum, sc1, bi1, p1t);
  k_conv2m<<<1024, 256, 0, stream>>>(p1t, qw2b, absum, h2t, s2, q2);
  k_fin<<<1, 128, 0, stream>>>(s2, q2, g2, b2, sc2, bi2, 128, 1.f/262144.f);
  k_pool2t<<<1024, 256, 0, stream>>>(h2t, p2, sc2, bi2);
  k_fc1m<<<dim3(8, 2, 16), 256, 0, stream>>>(p2, qfc1b, absum, h3p);
  k_fin3f<<<dim3(8, 8), 256, 0, stream>>>(h3p, h3, s3, q3);
  k_fin<<<1, 256, 0, stream>>>(s3, q3, g3, b3, sc3, bi3, 256, 1.f/1024.f);
  k_fc2<<<1024, 64, 0, stream>>>(h3, qwfc2, absum, sc3, bi3, out);
}

// Round 6
// 445.015 us; speedup vs baseline: 2.1145x; 2.1145x over previous
//
#include <hip/hip_runtime.h>
#include <stdint.h>

typedef unsigned short u16;
typedef unsigned int u32;
typedef __attribute__((ext_vector_type(8))) short s8v;   // 8 bf16 = 4 VGPR (MFMA A/B frag)
typedef __attribute__((ext_vector_type(4))) float f4v;   // MFMA C/D frag
typedef __attribute__((ext_vector_type(8))) u16 u16x8;

// ---------- bf16 helpers ----------
__device__ __forceinline__ float bf2f(u16 u){
  union { u32 i; float f; } v; v.i = ((u32)u) << 16; return v.f;
}
__device__ __forceinline__ u16 f2bf(float f){
  union { float f; u32 i; } v; v.f = f;
  u32 i = v.i;
  return (u16)((i + 0x7fffu + ((i >> 16) & 1u)) >> 16); // RNE
}
__device__ __forceinline__ float sgnf(float w){
  return (w > 0.f) ? 1.f : ((w < 0.f) ? -1.f : 0.f);
}
__device__ __forceinline__ u16 sgn_bf(float w){
  return (w > 0.f) ? (u16)0x3F80 : ((w < 0.f) ? (u16)0xBF80 : (u16)0);
}

// ---------- block reduction (256 threads = 4 waves) ----------
__device__ __forceinline__ void block_reduce2(float& a, float& b){
  #pragma unroll
  for (int off = 32; off > 0; off >>= 1){
    a += __shfl_down(a, off);
    b += __shfl_down(b, off);
  }
  __shared__ float ra[4], rb[4];
  int lane = threadIdx.x & 63, w = threadIdx.x >> 6;
  __syncthreads();
  if (lane == 0){ ra[w] = a; rb[w] = b; }
  __syncthreads();
  if (threadIdx.x == 0){
    a = ra[0] + ra[1] + ra[2] + ra[3];
    b = rb[0] + rb[1] + rb[2] + rb[3];
  }
}

__global__ void k_zero(float* __restrict__ p, int n){
  int i = blockIdx.x * blockDim.x + threadIdx.x;
  if (i < n) p[i] = 0.f;
}

// ---------- sum(|w|) for the 4 weight tensors ----------
__global__ __launch_bounds__(256) void k_absum(const float* __restrict__ w1, const float* __restrict__ w2,
                                               const float* __restrict__ wfc1, const float* __restrict__ wfc2,
                                               float* __restrict__ absum){
  int b = blockIdx.x, t = threadIdx.x;
  const float* src; int n0, cnt, slot;
  if (b < 64)      { src = wfc1; slot = 2; cnt = 2097152/64; n0 = b * cnt; }
  else if (b < 96) { src = w2;   slot = 1; cnt = 73728/32;   n0 = (b-64) * cnt; }
  else if (b == 96){ src = w1;   slot = 0; cnt = 1728;       n0 = 0; }
  else             { src = wfc2; slot = 3; cnt = 2560;       n0 = 0; }
  float s = 0.f, d = 0.f;
  for (int i = t; i < cnt; i += 256) s += fabsf(src[n0 + i]);
  block_reduce2(s, d);
  if (t == 0) atomicAdd(absum + slot, s);
}

// ---------- generate all quantized weight forms ----------
// qw1t: fp32 [27 k][64 co] for conv1 VALU
// qw2b: bf16 MFMA B-frags for conv2, frag fid=(s*2+ks)*8+nt, elem idx=fid*512+lane*8+j
//       co = (lane&15)*8 + nt   (co permutation -> coalesced channel-last stores)
//       c  = ks*32 + (lane>>4)*8 + j
// qfc1b: bf16 MFMA B-frags for fc1, frag = kstep*16+nt; k_phys = kstep*32+(lane>>4)*8+j
//       p2 is channel-last: k_phys = px*128+c  ->  logical k = c*64+px
// qwfc2: fp32 sign [10][256]
__global__ __launch_bounds__(256) void k_signgen(const float* __restrict__ w1, const float* __restrict__ w2,
                                                 const float* __restrict__ wfc1, const float* __restrict__ wfc2,
                                                 float* __restrict__ qw1t, u16* __restrict__ qw2b,
                                                 u16* __restrict__ qfc1b, float* __restrict__ qwfc2){
  int i = blockIdx.x * 256 + threadIdx.x;
  if (i < 2097152){
    int j = i & 7, lane = (i >> 3) & 63, fid = i >> 9;
    int kstep = fid >> 4, nt = fid & 15;
    int co = nt*16 + (lane & 15);
    int k_phys = kstep*32 + (lane >> 4)*8 + j;
    int px = k_phys >> 7, c = k_phys & 127;
    qfc1b[i] = sgn_bf(wfc1[(size_t)co*8192 + c*64 + px]);
  } else if (i < 2097152 + 73728){
    int i2 = i - 2097152;
    int j = i2 & 7, lane = (i2 >> 3) & 63, fid = i2 >> 9;  // 0..143
    int s = fid >> 4, ks = (fid >> 3) & 1, nt = fid & 7;
    int co = (lane & 15)*8 + nt;
    int c = ks*32 + (lane >> 4)*8 + j;
    qw2b[i2] = sgn_bf(w2[((size_t)co*64 + c)*9 + s]);
  } else if (i < 2097152 + 73728 + 1728){
    int i3 = i - (2097152 + 73728);
    int co = i3 / 27, k = i3 % 27;
    qw1t[k*64 + co] = sgnf(w1[i3]);
  } else if (i < 2097152 + 73728 + 1728 + 2560){
    int i4 = i - (2097152 + 73728 + 1728);
    qwfc2[i4] = sgnf(wfc2[i4]);
  }
}

// ---------- conv1 fused: conv + BN1 stats (pre-pool) + 2x2 pool-max -> p1raw ----------
// p1raw[1024][256px][64c] holds max4(conv)*alpha as bf16 (BN affine applied later by k_bn1;
// exact since scale>0). Stats are over all 1024*1024 pre-pool conv*alpha values.
// NOTE: no launch_bounds -- (256,4) caused a 64-VGPR cap + scratch spills (R5: 581 MB FETCH).
__global__ void k_conv1f(const float* __restrict__ x, const float* __restrict__ qw1t,
                         const float* __restrict__ absum, u16* __restrict__ p1raw,
                         float* __restrict__ gs, float* __restrict__ gq){
  __shared__ float xs[3*34*36]; // [ci][y 0..33][x 0..35], data y=1..32, x=2..33
  __shared__ float ls1[64], ls2[64];
  int n = blockIdx.x, t = threadIdx.x;
  if (t < 64){ ls1[t] = 0.f; ls2[t] = 0.f; }
  for (int i = t; i < 3672; i += 256) xs[i] = 0.f;
  __syncthreads();
  const float4* xg = (const float4*)(x + (size_t)n * 3072);
  for (int i = t; i < 768; i += 256){
    float4 v = xg[i];
    int ci = i >> 8, rem = i & 255, y = rem >> 3, xq = (rem & 7) * 4;
    int base = ci*1224 + (y+1)*36 + 2 + xq;
    xs[base+0] = v.x; xs[base+1] = v.y; xs[base+2] = v.z; xs[base+3] = v.w;
  }
  __syncthreads();
  float alpha = absum[0] * (1.f/1728.f);
  int lane = t & 63;
  int oy = t >> 4, ox = t & 15;   // output pixel; quad = input (2oy+sy, 2ox+sx)
  u16x8 pk[8];
  for (int cc = 0; cc < 8; ++cc){
    float acc[4][8];
    #pragma unroll
    for (int s = 0; s < 4; ++s)
      #pragma unroll
      for (int r = 0; r < 8; ++r) acc[s][r] = 0.f;
    for (int ci = 0; ci < 3; ++ci){
      #pragma unroll
      for (int dy = 0; dy < 3; ++dy){
        #pragma unroll
        for (int dx = 0; dx < 3; ++dx){
          int k = ci*9 + dy*3 + dx;
          float wv[8];
          #pragma unroll
          for (int r = 0; r < 8; ++r) wv[r] = qw1t[k*64 + cc*8 + r]; // uniform -> s_load
          #pragma unroll
          for (int s = 0; s < 4; ++s){
            float a = xs[ci*1224 + (2*oy + (s>>1) + dy)*36 + (2*ox + (s&1) + dx + 1)];
            #pragma unroll
            for (int r = 0; r < 8; ++r) acc[s][r] += a * wv[r];
          }
        }
      }
    }
    // fused stats on raw conv values (alpha folded in at the end)
    float s1v[8], s2v[8];
    #pragma unroll
    for (int r = 0; r < 8; ++r){
      s1v[r] = acc[0][r] + acc[1][r] + acc[2][r] + acc[3][r];
      s2v[r] = acc[0][r]*acc[0][r] + acc[1][r]*acc[1][r] + acc[2][r]*acc[2][r] + acc[3][r]*acc[3][r];
    }
    #pragma unroll
    for (int r = 0; r < 8; ++r){
      #pragma unroll
      for (int off = 32; off > 0; off >>= 1){
        s1v[r] += __shfl_xor(s1v[r], off);
        s2v[r] += __shfl_xor(s2v[r], off);
      }
    }
    if (lane == 0){
      #pragma unroll
      for (int r = 0; r < 8; ++r){
        atomicAdd(&ls1[cc*8 + r], s1v[r]);
        atomicAdd(&ls2[cc*8 + r], s2v[r]);
      }
    }
    // pool-max (pre-BN; exact because BN scale > 0)
    #pragma unroll
    for (int r = 0; r < 8; ++r){
      float m = fmaxf(fmaxf(acc[0][r], acc[1][r]), fmaxf(acc[2][r], acc[3][r]));
      pk[cc][r] = f2bf(m * alpha);
    }
  }
  u16* dst = p1raw + ((size_t)n*256 + t)*64;
  #pragma unroll
  for (int cc = 0; cc < 8; ++cc) *(u16x8*)(dst + cc*8) = pk[cc];
  __syncthreads();
  if (t < 64){
    atomicAdd(gs + t, ls1[t] * alpha);
    atomicAdd(gq + t, ls2[t] * alpha * alpha);
  }
}

// ---------- finalize BN affine params ----------
__global__ void k_fin(const float* __restrict__ sum, const float* __restrict__ sumsq,
                      const float* __restrict__ g, const float* __restrict__ b,
                      float* __restrict__ scale, float* __restrict__ bias, int C, float invc){
  int c = blockIdx.x * blockDim.x + threadIdx.x;
  if (c >= C) return;
  float m = sum[c] * invc;
  float var = sumsq[c] * invc - m*m;
  float sc = g[c] * rsqrtf(var + 1e-5f);
  scale[c] = sc;
  bias[c] = b[c] - m * sc;
}

// ---------- BN1 affine + ReLU, in-place on p1[1024][256px][64c] ----------
__global__ __launch_bounds__(256) void k_bn1(u16* __restrict__ p1, const float* __restrict__ sc,
                                             const float* __restrict__ bi){
  __shared__ float lsc[64], lbi[64];
  int t = threadIdx.x;
  if (t < 64) lsc[t] = sc[t];
  else if (t < 128) lbi[t - 64] = bi[t - 64];
  __syncthreads();
  size_t i = (size_t)blockIdx.x * 256 + t;
  int c0 = ((int)(i & 7)) * 8;
  u16x8 v = *(u16x8*)(p1 + i*8);
  u16x8 o;
  #pragma unroll
  for (int j = 0; j < 8; ++j)
    o[j] = f2bf(fmaxf(bf2f(v[j]) * lsc[c0+j] + lbi[c0+j], 0.f));
  *(u16x8*)(p1 + i*8) = o;
}

// ---------- conv2 via MFMA, barrier-free K-loop ----------
// p1t[1024][256px][64c] -> h2t[1024][256px][128co] bf16 (co permutation baked into qw2b).
// Fused BN2 stats. Per block: one image. Wave w: rows y = w*4..w*4+3, all 128 co.
__global__ __launch_bounds__(256, 2) void k_conv2m(const u16* __restrict__ p1t, const u16* __restrict__ qw2b,
                                                   const float* __restrict__ absum, u16* __restrict__ h2t,
                                                   float* __restrict__ gs, float* __restrict__ gq){
  __shared__ __align__(16) u16 img[16384];   // 32 KB, XOR-swizzled 16B units
  __shared__ float ls1[128], ls2[128];
  int n = blockIdx.x, t = threadIdx.x;
  if (t < 128){ ls1[t] = 0.f; ls2[t] = 0.f; }
  const u16* src = p1t + (size_t)n * 16384;
  #pragma unroll
  for (int i = 0; i < 8; ++i){
    int id = i*256 + t;            // = px*8 + unit
    int px = id >> 3, unit = id & 7;
    int su = unit ^ (px & 7);
    *(u16x8*)(img + px*64 + su*8) = *(const u16x8*)(src + id*8);
  }
  __syncthreads();
  int w = t >> 6, lane = t & 63, l15 = lane & 15, q = lane >> 4;
  const s8v* bp = (const s8v*)qw2b;
  f4v acc[4][8];
  #pragma unroll
  for (int a = 0; a < 4; ++a)
    #pragma unroll
    for (int b = 0; b < 8; ++b) acc[a][b] = (f4v)(0.0f);
  for (int dy = 0; dy < 3; ++dy){
    for (int dx = 0; dx < 3; ++dx){
      int s = dy*3 + dx;
      int xv = l15 + dx - 1;
      bool vx = (xv >= 0) && (xv < 16);
      int xc = min(max(xv, 0), 15);
      #pragma unroll
      for (int ks = 0; ks < 2; ++ks){
        s8v bf[8];
        #pragma unroll
        for (int nt = 0; nt < 8; ++nt) bf[nt] = bp[((s*2 + ks)*8 + nt)*64 + lane];
        #pragma unroll
        for (int mt = 0; mt < 4; ++mt){
          int yv = w*4 + mt + dy - 1;
          if (yv < 0 || yv > 15) continue;
          int px = yv*16 + xc;
          int su = (ks*4 + q) ^ (px & 7);
          s8v av = *(const s8v*)(img + px*64 + su*8);
          if (!vx) av = (s8v)(short)0;
          #pragma unroll
          for (int nt = 0; nt < 8; ++nt)
            acc[mt][nt] = __builtin_amdgcn_mfma_f32_16x16x32_bf16(av, bf[nt], acc[mt][nt], 0, 0, 0);
        }
      }
    }
  }
  float alpha = absum[1] * (1.f/73728.f);
  float s1v[8], s2v[8];
  #pragma unroll
  for (int nt = 0; nt < 8; ++nt){ s1v[nt] = 0.f; s2v[nt] = 0.f; }
  #pragma unroll
  for (int mt = 0; mt < 4; ++mt){
    int y = w*4 + mt;
    #pragma unroll
    for (int r = 0; r < 4; ++r){
      int px = y*16 + q*4 + r;
      u16x8 pk;
      #pragma unroll
      for (int nt = 0; nt < 8; ++nt){
        float v = acc[mt][nt][r] * alpha;
        s1v[nt] += v; s2v[nt] += v*v;
        pk[nt] = f2bf(v);
      }
      *(u16x8*)(h2t + ((size_t)n*256 + px)*128 + l15*8) = pk;
    }
  }
  #pragma unroll
  for (int nt = 0; nt < 8; ++nt){
    s1v[nt] += __shfl_xor(s1v[nt], 16); s1v[nt] += __shfl_xor(s1v[nt], 32);
    s2v[nt] += __shfl_xor(s2v[nt], 16); s2v[nt] += __shfl_xor(s2v[nt], 32);
  }
  if (q == 0){
    #pragma unroll
    for (int nt = 0; nt < 8; ++nt){
      atomicAdd(&ls1[l15*8 + nt], s1v[nt]);
      atomicAdd(&ls2[l15*8 + nt], s2v[nt]);
    }
  }
  __syncthreads();
  if (t < 128){ atomicAdd(gs + t, ls1[t]); atomicAdd(gq + t, ls2[t]); }
}

// ---------- BN2+ReLU+pool channel-last: h2t[1024][16x16][128] -> p2[1024][8x8][128] ----------
__global__ __launch_bounds__(256) void k_pool2t(const u16* __restrict__ h2t, u16* __restrict__ p2,
                                                const float* __restrict__ sc, const float* __restrict__ bi){
  __shared__ float lsc[128], lbi[128];
  int n = blockIdx.x, t = threadIdx.x;
  if (t < 128) lsc[t] = sc[t];
  else lbi[t - 128] = bi[t - 128];
  __syncthreads();
  int opx = t >> 2, cq = t & 3;
  int oy = opx >> 3, ox = opx & 7;
  const u16* base = h2t + (size_t)n*32768 + ((oy*2)*16 + ox*2)*128 + cq*32;
  u16* dst = p2 + (size_t)n*8192 + opx*128 + cq*32;
  #pragma unroll
  for (int v = 0; v < 4; ++v){
    u16x8 a0 = *(const u16x8*)(base + v*8);
    u16x8 a1 = *(const u16x8*)(base + 128 + v*8);
    u16x8 a2 = *(const u16x8*)(base + 2048 + v*8);
    u16x8 a3 = *(const u16x8*)(base + 2176 + v*8);
    u16x8 o;
    #pragma unroll
    for (int j = 0; j < 8; ++j){
      int c = cq*32 + v*8 + j;
      float m = fmaxf(fmaxf(bf2f(a0[j]), bf2f(a1[j])), fmaxf(bf2f(a2[j]), bf2f(a3[j])));
      o[j] = f2bf(fmaxf(m * lsc[c] + lbi[c], 0.f));
    }
    *(u16x8*)(dst + v*8) = o;
  }
}

// ---------- fc1 via MFMA, k-split 16: p2[1024][8192] x signs -> h3p[16][1024][256] ----------
__global__ __launch_bounds__(256) void k_fc1m(const u16* __restrict__ p2, const u16* __restrict__ qfc1b,
                                              const float* __restrict__ absum, float* __restrict__ h3p){
  int t = threadIdx.x;
  int bm = blockIdx.x, bn = blockIdx.y, kb = blockIdx.z;
  int w = t >> 6, lane = t & 63, l15 = lane & 15, q = lane >> 4;
  int rowbase = bm*128 + (w >> 1)*64;
  int ntb = bn*8 + (w & 1)*4;
  const s8v* bp = (const s8v*)qfc1b;
  f4v acc[4][4];
  #pragma unroll
  for (int a = 0; a < 4; ++a)
    #pragma unroll
    for (int b = 0; b < 4; ++b) acc[a][b] = (f4v)(0.0f);
  #pragma unroll 2
  for (int ks = 0; ks < 16; ++ks){
    int kst = kb*16 + ks;
    s8v bf[4], af[4];
    #pragma unroll
    for (int nt = 0; nt < 4; ++nt) bf[nt] = bp[(kst*16 + ntb + nt)*64 + lane];
    #pragma unroll
    for (int mt = 0; mt < 4; ++mt)
      af[mt] = *(const s8v*)(p2 + (size_t)(rowbase + mt*16 + l15)*8192 + kst*32 + q*8);
    #pragma unroll
    for (int mt = 0; mt < 4; ++mt)
      #pragma unroll
      for (int nt = 0; nt < 4; ++nt)
        acc[mt][nt] = __builtin_amdgcn_mfma_f32_16x16x32_bf16(af[mt], bf[nt], acc[mt][nt], 0, 0, 0);
  }
  float alpha = absum[2] * (1.f/2097152.f);
  float* dst = h3p + (size_t)kb * 262144;
  #pragma unroll
  for (int mt = 0; mt < 4; ++mt)
    #pragma unroll
    for (int nt = 0; nt < 4; ++nt){
      int col = (ntb + nt)*16 + l15;
      #pragma unroll
      for (int r = 0; r < 4; ++r)
        dst[(size_t)(rowbase + mt*16 + q*4 + r)*256 + col] = acc[mt][nt][r] * alpha;
    }
}

// ---------- reduce k-split slabs + BN3 stats + materialize h3 ----------
__global__ __launch_bounds__(256) void k_fin3f(const float* __restrict__ h3p, float* __restrict__ h3,
                                               float* __restrict__ s3, float* __restrict__ q3){
  int jb = blockIdx.x, ns = blockIdx.y, t = threadIdx.x;
  int jj = t & 31, nn = t >> 5;
  int j = jb*32 + jj;
  float s1 = 0.f, s2 = 0.f;
  for (int i = nn; i < 128; i += 8){
    int n = i*8 + ns;
    float v = 0.f;
    #pragma unroll 8
    for (int kb = 0; kb < 16; ++kb) v += h3p[(size_t)kb*262144 + n*256 + j];
    h3[n*256 + j] = v;
    s1 += v; s2 += v*v;
  }
  __shared__ float l1[256], l2[256];
  l1[t] = s1; l2[t] = s2;
  __syncthreads();
  if (t < 32){
    float a = 0.f, b = 0.f;
    #pragma unroll
    for (int k = 0; k < 8; ++k){ a += l1[t+32*k]; b += l2[t+32*k]; }
    atomicAdd(s3 + jb*32 + t, a); atomicAdd(q3 + jb*32 + t, b);
  }
}

// ---------- fc2: relu(bn3(h3)) @ sign(wfc2)^T -> out[1024,10] fp32 ----------
__global__ __launch_bounds__(64) void k_fc2(const float* __restrict__ h3, const float* __restrict__ qwfc2,
                                            const float* __restrict__ absum, const float* __restrict__ scale,
                                            const float* __restrict__ bias, float* __restrict__ out){
  int n = blockIdx.x, lane = threadIdx.x;
  float a[4];
  #pragma unroll
  for (int i = 0; i < 4; ++i){
    int j = lane + 64*i;
    float v = h3[(size_t)n*256 + j] * scale[j] + bias[j];
    a[i] = fmaxf(v, 0.f);
  }
  float alpha = absum[3] * (1.f/2560.f);
  #pragma unroll
  for (int k = 0; k < 10; ++k){
    float p = 0.f;
    #pragma unroll
    for (int i = 0; i < 4; ++i) p += a[i] * qwfc2[k*256 + lane + 64*i];
    #pragma unroll
    for (int off = 32; off > 0; off >>= 1) p += __shfl_down(p, off);
    if (lane == 0) out[n*10 + k] = p * alpha;
  }
}

extern "C" void kernel_launch(void* const* d_in, const int* in_sizes, int n_in,
                              void* d_out, int out_size, void* d_ws, size_t ws_size,
                              hipStream_t stream){
  (void)in_sizes; (void)n_in; (void)out_size; (void)ws_size;
  const float* x    = (const float*)d_in[0];
  const float* w1   = (const float*)d_in[1];
  const float* g1   = (const float*)d_in[2];
  const float* b1   = (const float*)d_in[3];
  const float* w2   = (const float*)d_in[4];
  const float* g2   = (const float*)d_in[5];
  const float* b2   = (const float*)d_in[6];
  const float* wfc1 = (const float*)d_in[7];
  const float* g3   = (const float*)d_in[8];
  const float* b3   = (const float*)d_in[9];
  const float* wfc2 = (const float*)d_in[10];
  float* out = (float*)d_out;

  float* wsf = (float*)d_ws;
  char*  wsb = (char*)d_ws;
  float* absum = wsf;
  float* s1 = wsf + 16;   float* q1 = wsf + 80;
  float* s2 = wsf + 144;  float* q2 = wsf + 272;
  float* s3 = wsf + 1024; float* q3 = wsf + 1280;
  float* sc1 = wsf + 1536; float* bi1 = wsf + 1600;
  float* sc2 = wsf + 1664; float* bi2 = wsf + 1792;
  float* sc3 = wsf + 2048; float* bi3 = wsf + 2304;
  float* qw1t  = wsf + 4096;                         // 1728 fp32
  u16*   qw2b  = (u16*)(wsb + (64u << 10));          // 144 KB bf16 B-frags
  float* qwfc2 = (float*)(wsb + (256u << 10));       // 10 KB fp32
  float* h3    = (float*)(wsb + (1ull << 20));       // 1 MB fp32 [1024][256]
  u16*   qfc1b = (u16*)(wsb + (2ull << 20));         // 4 MB bf16 B-frags
  u16*   p1t   = (u16*)(wsb + (8ull << 20) + 4096);  // 32 MB bf16 [1024][256][64]
  u16*   h2t   = (u16*)(wsb + (48ull << 20));        // 64 MB bf16 [1024][256][128]
  u16*   p2    = (u16*)(wsb + (112ull << 20));       // 16 MB bf16 [1024][8192] (channel-last k)
  float* h3p   = (float*)(wsb + (128ull << 20));     // 16 MB fp32 [16][1024][256]

  k_zero<<<10, 256, 0, stream>>>(wsf, 2560);
  k_absum<<<98, 256, 0, stream>>>(w1, w2, wfc1, wfc2, absum);
  k_signgen<<<8498, 256, 0, stream>>>(w1, w2, wfc1, wfc2, qw1t, qw2b, qfc1b, qwfc2);
  k_conv1f<<<1024, 256, 0, stream>>>(x, qw1t, absum, p1t, s1, q1);
  k_fin<<<1, 64, 0, stream>>>(s1, q1, g1, b1, sc1, bi1, 64, 1.f/1048576.f);
  k_bn1<<<8192, 256, 0, stream>>>(p1t, sc1, bi1);
  k_conv2m<<<1024, 256, 0, stream>>>(p1t, qw2b, absum, h2t, s2, q2);
  k_fin<<<1, 128, 0, stream>>>(s2, q2, g2, b2, sc2, bi2, 128, 1.f/262144.f);
  k_pool2t<<<1024, 256, 0, stream>>>(h2t, p2, sc2, bi2);
  k_fc1m<<<dim3(8, 2, 16), 256, 0, stream>>>(p2, qfc1b, absum, h3p);
  k_fin3f<<<dim3(8, 8), 256, 0, stream>>>(h3p, h3, s3, q3);
  k_fin<<<1, 256, 0, stream>>>(s3, q3, g3, b3, sc3, bi3, 256, 1.f/1024.f);
  k_fc2<<<1024, 64, 0, stream>>>(h3, qwfc2, absum, sc3, bi3, out);
}